// Round 5
// baseline (310.728 us; speedup 1.0000x reference)
//
#include <hip/hip_runtime.h>
#include <hip/hip_bf16.h>

#define N_NODES 50000
#define N_EDGES 1600000
#define N_GRAPHS 512
#define VOCAB 1000
#define EMB 32
#define HID 64
#define N_CLASS 2

#define NPART 8
#define PART_NODES (N_NODES / NPART)   // 6250
#define MAXDEG 96                      // Poisson(32) tail @96 ~ 4e-20/node

__device__ __forceinline__ float bf2f(unsigned short u) {
    union { unsigned int i; float f; } c;
    c.i = ((unsigned int)u) << 16;
    return c.f;
}

// ---------------- CSR build: dst-partitioned, padded (no hist/scan) ----------------
// csr[d*MAXDEG + pos] = (cls << 16) | src ; cursor[d] = degree
__global__ __launch_bounds__(256) void fill_part_kernel(
        const int* __restrict__ src, const int* __restrict__ dst,
        const int* __restrict__ x_ids, int* __restrict__ cursor,
        int* __restrict__ csr) {
    int p = blockIdx.x & (NPART - 1);       // partition (XCD round-robin heuristic)
    int bp = blockIdx.x >> 3;
    int nblk = gridDim.x >> 3;
    int lo = p * PART_NODES, hi = lo + PART_NODES;
    int stride = nblk * blockDim.x;
    for (int i = bp * blockDim.x + threadIdx.x; i < N_EDGES; i += stride) {
        int d = dst[i];
        if (d >= lo && d < hi) {
            int pos = atomicAdd(&cursor[d], 1);
            int sn = src[i];
            csr[d * MAXDEG + pos] = (x_ids[sn] << 16) | sn;
        }
    }
}

// ---------------- precompute folded layer-1 tables ----------------
// e1 = embed @ w1l  (VOCAB x HID), e1r = embed @ w1r
__global__ void precompute_e1_kernel(const float* __restrict__ embed,
                                     const float* __restrict__ w1l,
                                     const float* __restrict__ w1r,
                                     float* __restrict__ e1, float* __restrict__ e1r) {
    int id = blockIdx.x * blockDim.x + threadIdx.x;
    if (id >= VOCAB * HID) return;
    int v = id >> 6, j = id & 63;
    float a = 0.0f, b = 0.0f;
    #pragma unroll
    for (int k = 0; k < EMB; ++k) {
        float ev = embed[v * EMB + k];
        a = fmaf(ev, w1l[k * HID + j], a);
        b = fmaf(ev, w1r[k * HID + j], b);
    }
    e1[id] = a;
    e1r[id] = b;
}

// ---------------- layer 1: agg (float4 quarter-wave gather) + linear + relu ----------------
// h1[i][j] = relu( b1[j] + mean_{k in N(i)} e1[cls_k][j] + e1r[x_ids[i]][j] )
__global__ __launch_bounds__(256) void agg1_lin1_kernel(
        const int* __restrict__ x_ids, const int* __restrict__ csr,
        const int* __restrict__ deg_arr, const float* __restrict__ e1,
        const float* __restrict__ e1r, const float* __restrict__ b1,
        float* __restrict__ h1, __hip_bfloat16* __restrict__ h1b) {
    __shared__ float lds_mean[4][HID];
    int id = blockIdx.x * blockDim.x + threadIdx.x;
    int i = id >> 6, j = id & 63;     // wave-uniform node i
    int lane = threadIdx.x & 63;
    int w = threadIdx.x >> 6;
    int q = lane >> 4, fl = lane & 15;
    int s = i * MAXDEG;
    int deg = deg_arr[i];
    int e = s + deg;
    float4 acc[8];
    #pragma unroll
    for (int t = 0; t < 8; ++t) acc[t] = make_float4(0.f, 0.f, 0.f, 0.f);
    for (int k = s; k < e; k += 32) {
        #pragma unroll
        for (int t = 0; t < 8; ++t) {
            int idx = k + (t << 2) + q;       // quarter q takes edge idx
            if (idx < e) {
                int c = csr[idx] >> 16;
                float4 v = *reinterpret_cast<const float4*>(e1 + c * HID + (fl << 2));
                acc[t].x += v.x; acc[t].y += v.y; acc[t].z += v.z; acc[t].w += v.w;
            }
        }
    }
    float4 a = acc[0];
    #pragma unroll
    for (int t = 1; t < 8; ++t) {
        a.x += acc[t].x; a.y += acc[t].y; a.z += acc[t].z; a.w += acc[t].w;
    }
    // combine quarters: butterfly over xor 16, 32
    a.x += __shfl_xor(a.x, 16); a.y += __shfl_xor(a.y, 16);
    a.z += __shfl_xor(a.z, 16); a.w += __shfl_xor(a.w, 16);
    a.x += __shfl_xor(a.x, 32); a.y += __shfl_xor(a.y, 32);
    a.z += __shfl_xor(a.z, 32); a.w += __shfl_xor(a.w, 32);
    float inv = 1.0f / fmaxf((float)deg, 1.0f);
    if (lane < 16) {
        float4 m = make_float4(a.x * inv, a.y * inv, a.z * inv, a.w * inv);
        *reinterpret_cast<float4*>(&lds_mean[w][fl << 2]) = m;
    }
    __syncthreads();
    float h = fmaxf(lds_mean[w][j] + b1[j] + e1r[x_ids[i] * HID + j], 0.0f);
    h1[id] = h;
    h1b[id] = __float2bfloat16(h);
}

// ---------------- layer 2: agg (ushort4 bf16 quarter-wave gather) + linear + relu + pool ----
__global__ __launch_bounds__(256) void agg2_lin2_pool_kernel(
        const float* __restrict__ h1, const __hip_bfloat16* __restrict__ h1b,
        const int* __restrict__ csr, const int* __restrict__ deg_arr,
        const float* __restrict__ w2l, const float* __restrict__ b2,
        const float* __restrict__ w2r, const int* __restrict__ batch,
        float* __restrict__ gsum) {
    __shared__ float lds_mean[4][HID];
    __shared__ float lds_h[4][HID];
    int id = blockIdx.x * blockDim.x + threadIdx.x;
    int i = id >> 6, j = id & 63;
    int lane = threadIdx.x & 63;
    int w = threadIdx.x >> 6;
    int q = lane >> 4, fl = lane & 15;
    int s = i * MAXDEG;
    int deg = deg_arr[i];
    int e = s + deg;
    float4 acc[8];
    #pragma unroll
    for (int t = 0; t < 8; ++t) acc[t] = make_float4(0.f, 0.f, 0.f, 0.f);
    for (int k = s; k < e; k += 32) {
        #pragma unroll
        for (int t = 0; t < 8; ++t) {
            int idx = k + (t << 2) + q;
            if (idx < e) {
                int n = csr[idx] & 0xFFFF;
                ushort4 v = *reinterpret_cast<const ushort4*>(h1b + n * HID + (fl << 2));
                acc[t].x += bf2f(v.x); acc[t].y += bf2f(v.y);
                acc[t].z += bf2f(v.z); acc[t].w += bf2f(v.w);
            }
        }
    }
    float4 a = acc[0];
    #pragma unroll
    for (int t = 1; t < 8; ++t) {
        a.x += acc[t].x; a.y += acc[t].y; a.z += acc[t].z; a.w += acc[t].w;
    }
    a.x += __shfl_xor(a.x, 16); a.y += __shfl_xor(a.y, 16);
    a.z += __shfl_xor(a.z, 16); a.w += __shfl_xor(a.w, 16);
    a.x += __shfl_xor(a.x, 32); a.y += __shfl_xor(a.y, 32);
    a.z += __shfl_xor(a.z, 32); a.w += __shfl_xor(a.w, 32);
    float inv = 1.0f / fmaxf((float)deg, 1.0f);
    if (lane < 16) {
        float4 m = make_float4(a.x * inv, a.y * inv, a.z * inv, a.w * inv);
        *reinterpret_cast<float4*>(&lds_mean[w][fl << 2]) = m;
    }
    lds_h[w][j] = h1[i * HID + j];
    __syncthreads();
    float acc2 = b2[j];
    #pragma unroll
    for (int kk = 0; kk < HID; ++kk)
        acc2 = fmaf(lds_mean[w][kk], w2l[kk * HID + j],
                    fmaf(lds_h[w][kk], w2r[kk * HID + j], acc2));
    float h2 = fmaxf(acc2, 0.0f);
    atomicAdd(&gsum[batch[i] * HID + j], h2);
}

// ---------------- output: pool-normalize + final linear ----------------
__global__ void out_kernel(const float* __restrict__ gsum, const int* __restrict__ batch,
                           const float* __restrict__ w_out, const float* __restrict__ b_out,
                           float* __restrict__ out) {
    int id = blockIdx.x * blockDim.x + threadIdx.x;
    if (id >= N_GRAPHS * N_CLASS) return;
    int g = id >> 1, c = id & 1;
    int lo = 0, hi = N_NODES;
    while (lo < hi) { int mid = (lo + hi) >> 1; if (batch[mid] < g) lo = mid + 1; else hi = mid; }
    int first = lo;
    lo = 0; hi = N_NODES;
    while (lo < hi) { int mid = (lo + hi) >> 1; if (batch[mid] <= g) lo = mid + 1; else hi = mid; }
    float cnt = (float)(lo - first);
    float inv = 1.0f / fmaxf(cnt, 1.0f);
    float acc = b_out[c];
    #pragma unroll
    for (int j = 0; j < HID; ++j)
        acc = fmaf(gsum[g * HID + j] * inv, w_out[j * N_CLASS + c], acc);
    out[id] = acc;
}

// ---------------- launch ----------------

extern "C" void kernel_launch(void* const* d_in, const int* in_sizes, int n_in,
                              void* d_out, int out_size, void* d_ws, size_t ws_size,
                              hipStream_t stream) {
    const int*   x_ids = (const int*)d_in[0];
    const int*   edge  = (const int*)d_in[1];
    const int*   batch = (const int*)d_in[2];
    const float* embed = (const float*)d_in[3];
    const float* w1l   = (const float*)d_in[4];
    const float* b1    = (const float*)d_in[5];
    const float* w1r   = (const float*)d_in[6];
    const float* w2l   = (const float*)d_in[7];
    const float* b2    = (const float*)d_in[8];
    const float* w2r   = (const float*)d_in[9];
    const float* wout  = (const float*)d_in[10];
    const float* bout  = (const float*)d_in[11];
    const int* src = edge;
    const int* dst = edge + N_EDGES;
    float* out = (float*)d_out;

    char* ws = (char*)d_ws;
    size_t off = 0;
    auto alloc = [&](size_t bytes) -> void* {
        void* p = ws + off;
        off += (bytes + 255) & ~(size_t)255;
        return p;
    };
    float*           h1     = (float*)alloc((size_t)N_NODES * HID * 4);      // 12.8 MB
    __hip_bfloat16*  h1b    = (__hip_bfloat16*)alloc((size_t)N_NODES * HID * 2); // 6.4 MB
    int*             csr    = (int*)alloc((size_t)N_NODES * MAXDEG * 4);     // 19.2 MB padded
    int*             cursor = (int*)alloc((size_t)N_NODES * 4);              // 200 KB (degree)
    float*           e1     = (float*)alloc((size_t)VOCAB * HID * 4);        // 256 KB
    float*           e1r    = (float*)alloc((size_t)VOCAB * HID * 4);        // 256 KB
    float*           gsum   = (float*)alloc((size_t)N_GRAPHS * HID * 4);     // 128 KB

    hipMemsetAsync(cursor, 0, (size_t)N_NODES * 4, stream);
    hipMemsetAsync(gsum, 0, (size_t)N_GRAPHS * HID * 4, stream);

    const int B = 256;
    precompute_e1_kernel<<<(VOCAB * HID + B - 1) / B, B, 0, stream>>>(embed, w1l, w1r, e1, e1r);
    fill_part_kernel<<<NPART * 128, B, 0, stream>>>(src, dst, x_ids, cursor, csr);

    agg1_lin1_kernel<<<N_NODES * HID / B, B, 0, stream>>>(x_ids, csr, cursor,
                                                          e1, e1r, b1, h1, h1b);
    agg2_lin2_pool_kernel<<<N_NODES * HID / B, B, 0, stream>>>(h1, h1b, csr, cursor,
                                                               w2l, b2, w2r, batch, gsum);
    out_kernel<<<(N_GRAPHS * N_CLASS + B - 1) / B, B, 0, stream>>>(gsum, batch, wout, bout, out);
}

// Round 6
// 262.914 us; speedup vs baseline: 1.1819x; 1.1819x over previous
//
#include <hip/hip_runtime.h>
#include <hip/hip_bf16.h>

#define N_NODES 50000
#define N_EDGES 1600000
#define N_GRAPHS 512
#define VOCAB 1000
#define EMB 32
#define HID 64
#define N_CLASS 2

#define NPART 8
#define PART_NODES (N_NODES / NPART)   // 6250
#define MAXDEG 96                      // Poisson(32) tail @96 ~ 4e-20/node

#define L2P_BLOCKS 768                 // 3 blocks/CU co-resident
#define L2P_WAVES (L2P_BLOCKS * 4)     // 3072
#define L2P_CHUNK ((N_NODES + L2P_WAVES - 1) / L2P_WAVES)  // 17

__device__ __forceinline__ float bf2f(unsigned short u) {
    union { unsigned int i; float f; } c;
    c.i = ((unsigned int)u) << 16;
    return c.f;
}
__device__ __forceinline__ float rdlane(float v, int k) {
    return __int_as_float(__builtin_amdgcn_readlane(__float_as_int(v), k));
}

// ---------------- CSR build: dst-partitioned, padded ----------------
// csr[d*MAXDEG + pos] = (cls << 16) | src ; cursor[d] = degree
__global__ __launch_bounds__(256) void fill_part_kernel(
        const int* __restrict__ src, const int* __restrict__ dst,
        const int* __restrict__ x_ids, int* __restrict__ cursor,
        int* __restrict__ csr) {
    int p = blockIdx.x & (NPART - 1);
    int bp = blockIdx.x >> 3;
    int nblk = gridDim.x >> 3;
    int lo = p * PART_NODES, hi = lo + PART_NODES;
    int stride = nblk * blockDim.x;
    for (int i = bp * blockDim.x + threadIdx.x; i < N_EDGES; i += stride) {
        int d = dst[i];
        if (d >= lo && d < hi) {
            int pos = atomicAdd(&cursor[d], 1);
            int sn = src[i];
            csr[d * MAXDEG + pos] = (x_ids[sn] << 16) | sn;
        }
    }
}

// ---------------- precompute folded layer-1 tables ----------------
// e1b = bf16(embed @ w1l)  (VOCAB x HID), e1r = embed @ w1r (fp32)
__global__ void precompute_e1_kernel(const float* __restrict__ embed,
                                     const float* __restrict__ w1l,
                                     const float* __restrict__ w1r,
                                     __hip_bfloat16* __restrict__ e1b,
                                     float* __restrict__ e1r) {
    int id = blockIdx.x * blockDim.x + threadIdx.x;
    if (id >= VOCAB * HID) return;
    int v = id >> 6, j = id & 63;
    float a = 0.0f, b = 0.0f;
    #pragma unroll
    for (int k = 0; k < EMB; ++k) {
        float ev = embed[v * EMB + k];
        a = fmaf(ev, w1l[k * HID + j], a);
        b = fmaf(ev, w1r[k * HID + j], b);
    }
    e1b[id] = __float2bfloat16(a);
    e1r[id] = b;
}

// ---------------- layer 1: agg (bf16 class-table gather) + linear + relu ----------------
// h1[i][j] = relu( b1[j] + mean_{k in N(i)} e1[cls_k][j] + e1r[x_ids[i]][j] )
__global__ __launch_bounds__(256) void agg1_lin1_kernel(
        const int* __restrict__ x_ids, const int* __restrict__ csr,
        const int* __restrict__ deg_arr, const __hip_bfloat16* __restrict__ e1b,
        const float* __restrict__ e1r, const float* __restrict__ b1,
        float* __restrict__ h1, __hip_bfloat16* __restrict__ h1b) {
    int id = blockIdx.x * blockDim.x + threadIdx.x;
    int i = __builtin_amdgcn_readfirstlane(id >> 6);
    int j = threadIdx.x & 63;
    int s = i * MAXDEG;
    int deg = deg_arr[i];
    int e = s + deg;
    float s0 = 0.f, s1 = 0.f, s2 = 0.f, s3 = 0.f;
    float s4 = 0.f, s5 = 0.f, s6 = 0.f, s7 = 0.f;
    int k = s;
    for (; k + 8 <= e; k += 8) {
        int c0 = csr[k]     >> 16, c1 = csr[k + 1] >> 16;
        int c2 = csr[k + 2] >> 16, c3 = csr[k + 3] >> 16;
        int c4 = csr[k + 4] >> 16, c5 = csr[k + 5] >> 16;
        int c6 = csr[k + 6] >> 16, c7 = csr[k + 7] >> 16;
        s0 += (float)e1b[c0 * HID + j];
        s1 += (float)e1b[c1 * HID + j];
        s2 += (float)e1b[c2 * HID + j];
        s3 += (float)e1b[c3 * HID + j];
        s4 += (float)e1b[c4 * HID + j];
        s5 += (float)e1b[c5 * HID + j];
        s6 += (float)e1b[c6 * HID + j];
        s7 += (float)e1b[c7 * HID + j];
    }
    for (; k < e; ++k) s0 += (float)e1b[(csr[k] >> 16) * HID + j];
    float mean = ((s0 + s1) + (s2 + s3) + (s4 + s5) + (s6 + s7)) / fmaxf((float)deg, 1.0f);
    float h = fmaxf(mean + b1[j] + e1r[x_ids[i] * HID + j], 0.0f);
    int o = i * HID + j;
    h1[o] = h;
    h1b[o] = __float2bfloat16(h);
}

// ---------------- layer 2 aggregation only: mean2 = mean of h1b rows ----------------
__global__ __launch_bounds__(256) void agg2_mean_kernel(
        const __hip_bfloat16* __restrict__ h1b, const int* __restrict__ csr,
        const int* __restrict__ deg_arr, float* __restrict__ mean2) {
    int id = blockIdx.x * blockDim.x + threadIdx.x;
    int i = __builtin_amdgcn_readfirstlane(id >> 6);
    int j = threadIdx.x & 63;
    int s = i * MAXDEG;
    int deg = deg_arr[i];
    int e = s + deg;
    float s0 = 0.f, s1 = 0.f, s2 = 0.f, s3 = 0.f;
    float s4 = 0.f, s5 = 0.f, s6 = 0.f, s7 = 0.f;
    int k = s;
    for (; k + 8 <= e; k += 8) {
        int n0 = csr[k]     & 0xFFFF, n1 = csr[k + 1] & 0xFFFF;
        int n2 = csr[k + 2] & 0xFFFF, n3 = csr[k + 3] & 0xFFFF;
        int n4 = csr[k + 4] & 0xFFFF, n5 = csr[k + 5] & 0xFFFF;
        int n6 = csr[k + 6] & 0xFFFF, n7 = csr[k + 7] & 0xFFFF;
        s0 += (float)h1b[n0 * HID + j];
        s1 += (float)h1b[n1 * HID + j];
        s2 += (float)h1b[n2 * HID + j];
        s3 += (float)h1b[n3 * HID + j];
        s4 += (float)h1b[n4 * HID + j];
        s5 += (float)h1b[n5 * HID + j];
        s6 += (float)h1b[n6 * HID + j];
        s7 += (float)h1b[n7 * HID + j];
    }
    for (; k < e; ++k) s0 += (float)h1b[(csr[k] & 0xFFFF) * HID + j];
    float mean = ((s0 + s1) + (s2 + s3) + (s4 + s5) + (s6 + s7)) / fmaxf((float)deg, 1.0f);
    mean2[i * HID + j] = mean;
}

// ---------------- layer 2 linear + relu + pool: weights in VGPRs ----------------
// Each wave: weight columns (lane j) held in 128 VGPRs; contiguous node chunk;
// mean/h rows broadcast lane->all via v_readlane; pool sums accumulated locally
// per batch-sorted graph run, flushed with ~2 atomics per wave.
__global__ __launch_bounds__(256) void lin2_pool_kernel(
        const float* __restrict__ mean2, const float* __restrict__ h1,
        const float* __restrict__ w2l, const float* __restrict__ b2,
        const float* __restrict__ w2r, const int* __restrict__ batch,
        float* __restrict__ gsum) {
    int lane = threadIdx.x & 63;
    int wv = (blockIdx.x * blockDim.x + threadIdx.x) >> 6;   // global wave id
    int i0 = wv * L2P_CHUNK;
    int i1 = i0 + L2P_CHUNK; if (i1 > N_NODES) i1 = N_NODES;
    if (i0 >= N_NODES) return;
    float wl[HID], wr[HID];
    #pragma unroll
    for (int k = 0; k < HID; ++k) {
        wl[k] = w2l[k * HID + lane];
        wr[k] = w2r[k * HID + lane];
    }
    float bj = b2[lane];
    int curg = __builtin_amdgcn_readfirstlane(batch[i0]);
    float accp = 0.0f;
    float m = mean2[i0 * HID + lane];
    float h = h1[i0 * HID + lane];
    for (int i = i0; i < i1; ++i) {
        float mn = 0.f, hn = 0.f;
        if (i + 1 < i1) {                      // prefetch next rows
            mn = mean2[(i + 1) * HID + lane];
            hn = h1[(i + 1) * HID + lane];
        }
        int g = __builtin_amdgcn_readfirstlane(batch[i]);
        if (g != curg) {
            atomicAdd(&gsum[curg * HID + lane], accp);
            accp = 0.0f;
            curg = g;
        }
        float z = bj;
        #pragma unroll
        for (int k = 0; k < HID; ++k)
            z = fmaf(rdlane(m, k), wl[k], fmaf(rdlane(h, k), wr[k], z));
        accp += fmaxf(z, 0.0f);
        m = mn; h = hn;
    }
    atomicAdd(&gsum[curg * HID + lane], accp);
}

// ---------------- output: pool-normalize + final linear ----------------
__global__ void out_kernel(const float* __restrict__ gsum, const int* __restrict__ batch,
                           const float* __restrict__ w_out, const float* __restrict__ b_out,
                           float* __restrict__ out) {
    int id = blockIdx.x * blockDim.x + threadIdx.x;
    if (id >= N_GRAPHS * N_CLASS) return;
    int g = id >> 1, c = id & 1;
    int lo = 0, hi = N_NODES;
    while (lo < hi) { int mid = (lo + hi) >> 1; if (batch[mid] < g) lo = mid + 1; else hi = mid; }
    int first = lo;
    lo = 0; hi = N_NODES;
    while (lo < hi) { int mid = (lo + hi) >> 1; if (batch[mid] <= g) lo = mid + 1; else hi = mid; }
    float cnt = (float)(lo - first);
    float inv = 1.0f / fmaxf(cnt, 1.0f);
    float acc = b_out[c];
    #pragma unroll
    for (int j = 0; j < HID; ++j)
        acc = fmaf(gsum[g * HID + j] * inv, w_out[j * N_CLASS + c], acc);
    out[id] = acc;
}

// ---------------- launch ----------------

extern "C" void kernel_launch(void* const* d_in, const int* in_sizes, int n_in,
                              void* d_out, int out_size, void* d_ws, size_t ws_size,
                              hipStream_t stream) {
    const int*   x_ids = (const int*)d_in[0];
    const int*   edge  = (const int*)d_in[1];
    const int*   batch = (const int*)d_in[2];
    const float* embed = (const float*)d_in[3];
    const float* w1l   = (const float*)d_in[4];
    const float* b1    = (const float*)d_in[5];
    const float* w1r   = (const float*)d_in[6];
    const float* w2l   = (const float*)d_in[7];
    const float* b2    = (const float*)d_in[8];
    const float* w2r   = (const float*)d_in[9];
    const float* wout  = (const float*)d_in[10];
    const float* bout  = (const float*)d_in[11];
    const int* src = edge;
    const int* dst = edge + N_EDGES;
    float* out = (float*)d_out;

    char* ws = (char*)d_ws;
    size_t off = 0;
    auto alloc = [&](size_t bytes) -> void* {
        void* p = ws + off;
        off += (bytes + 255) & ~(size_t)255;
        return p;
    };
    float*           h1     = (float*)alloc((size_t)N_NODES * HID * 4);          // 12.8 MB
    __hip_bfloat16*  h1b    = (__hip_bfloat16*)alloc((size_t)N_NODES * HID * 2); // 6.4 MB
    float*           mean2  = (float*)alloc((size_t)N_NODES * HID * 4);          // 12.8 MB
    int*             csr    = (int*)alloc((size_t)N_NODES * MAXDEG * 4);         // 19.2 MB
    int*             cursor = (int*)alloc((size_t)N_NODES * 4);                  // 200 KB
    __hip_bfloat16*  e1b    = (__hip_bfloat16*)alloc((size_t)VOCAB * HID * 2);   // 128 KB
    float*           e1r    = (float*)alloc((size_t)VOCAB * HID * 4);            // 256 KB
    float*           gsum   = (float*)alloc((size_t)N_GRAPHS * HID * 4);         // 128 KB

    hipMemsetAsync(cursor, 0, (size_t)N_NODES * 4, stream);
    hipMemsetAsync(gsum, 0, (size_t)N_GRAPHS * HID * 4, stream);

    const int B = 256;
    precompute_e1_kernel<<<(VOCAB * HID + B - 1) / B, B, 0, stream>>>(embed, w1l, w1r, e1b, e1r);
    fill_part_kernel<<<NPART * 128, B, 0, stream>>>(src, dst, x_ids, cursor, csr);

    agg1_lin1_kernel<<<N_NODES * HID / B, B, 0, stream>>>(x_ids, csr, cursor,
                                                          e1b, e1r, b1, h1, h1b);
    agg2_mean_kernel<<<N_NODES * HID / B, B, 0, stream>>>(h1b, csr, cursor, mean2);
    lin2_pool_kernel<<<L2P_BLOCKS, B, 0, stream>>>(mean2, h1, w2l, b2, w2r, batch, gsum);
    out_kernel<<<(N_GRAPHS * N_CLASS + B - 1) / B, B, 0, stream>>>(gsum, batch, wout, bout, out);
}